// Round 3
// baseline (416.113 us; speedup 1.0000x reference)
//
#include <hip/hip_runtime.h>
#include <cmath>

typedef _Float16 f16;
typedef _Float16 f16x2 __attribute__((ext_vector_type(2)));
typedef _Float16 f16x4 __attribute__((ext_vector_type(4)));
typedef _Float16 f16x8 __attribute__((ext_vector_type(8)));
typedef float f32x4 __attribute__((ext_vector_type(4)));

namespace {

constexpr int kB = 8;
constexpr int kL = 680;
constexpr int kH = 24;
constexpr int kD = 64;
constexpr int kC = 1536;          // kH * kD
constexpr int kM = kB * kL;       // 5440
constexpr int kN3 = 3 * kC;       // 4608
constexpr int kNKT = 11;          // ceil(680/64)
constexpr int kNQT = 6;           // ceil(680/128)

#define ASYNC_CP16(gp, lp)                                          \
  __builtin_amdgcn_global_load_lds(                                 \
      (const __attribute__((address_space(1))) unsigned int*)(gp),  \
      (__attribute__((address_space(3))) unsigned int*)(lp), 16, 0, 0)

// Bijective XCD swizzle (m204): same-XCD blocks get contiguous linear ids
// so panel reuse lands in the XCD-private 4MB L2. Works for any nwg.
__device__ inline int xcd_swizzle(int bid, int nwg) {
  int q = nwg >> 3, r = nwg & 7;
  int x = bid & 7, idx = bid >> 3;
  return (x < r ? x * (q + 1) : r * (q + 1) + (x - r) * q) + idx;
}

// ------------------------------------------------------------- fp32 -> fp16
__global__ void cvt_f32_f16(const float* __restrict__ in,
                            f16* __restrict__ out, int n) {
  int i = (blockIdx.x * blockDim.x + threadIdx.x) * 4;
  if (i >= n) return;  // n is a multiple of 4 for all our arrays
  float4 v = *reinterpret_cast<const float4*>(&in[i]);
  f16x4 o;
  o[0] = (f16)v.x;
  o[1] = (f16)v.y;
  o[2] = (f16)v.z;
  o[3] = (f16)v.w;
  *reinterpret_cast<f16x4*>(&out[i]) = o;
}

// ---------------------------------------------------------------- bias build
__global__ void build_bias_kernel(const float* __restrict__ qb,
                                  const float* __restrict__ vb,
                                  float* __restrict__ bias) {
  int i = blockIdx.x * blockDim.x + threadIdx.x;
  if (i >= kN3) return;
  float v = 0.0f;
  if (i < kC) v = qb[i];
  else if (i >= 2 * kC) v = vb[i - 2 * kC];
  bias[i] = v;
}

// ------------------------------------------- v4 GEMM (proj / small-N path)
// Round-0 verified kernel + T1 XCD swizzle. Used where the 256^2 grid would
// under-subscribe the GPU (proj: N=1536 -> 132 blocks < 256 CUs).
template <typename OutT>
__global__ __launch_bounds__(256, 2) void gemm_f16(
    const f16* __restrict__ A, const f16* __restrict__ Bw,
    const float* __restrict__ bias, OutT* __restrict__ Cm,
    int M, int N, int K) {
  constexpr int BM = 128, BN = 256, BK = 64;
  __shared__ __align__(16) f16 As[BM * BK];   // 16 KB, k-major 16B blocks
  __shared__ __align__(16) f16 Bs[BN * BK];   // 32 KB
  const int tid = threadIdx.x;
  const int w = tid >> 6;
  const int lane = tid & 63;
  const int lr = lane & 15;
  const int quad = lane >> 4;
  const int wm = (w & 1) * 64;
  const int wn = (w >> 1) * 128;
  const int gx = gridDim.x;
  const int sw = xcd_swizzle(blockIdx.y * gx + blockIdx.x, gx * gridDim.y);
  const int m0 = (sw / gx) * BM;
  const int n0 = (sw % gx) * BN;

  f32x4 acc[4][8];
#pragma unroll
  for (int i = 0; i < 4; ++i)
#pragma unroll
    for (int j = 0; j < 8; ++j)
#pragma unroll
      for (int c = 0; c < 4; ++c) acc[i][j][c] = 0.0f;

  int arow[4], akb[4];
#pragma unroll
  for (int n = 0; n < 4; ++n) {
    int La = (w * 4 + n) * 64 + lane;
    akb[n] = La >> 7;
    arow[n] = La & 127;
  }
  int brow[8], bkb[8];
#pragma unroll
  for (int n = 0; n < 8; ++n) {
    int Lb = (w * 8 + n) * 64 + lane;
    bkb[n] = Lb >> 8;
    brow[n] = Lb & 255;
  }

  for (int kt = 0; kt < K; kt += BK) {
#pragma unroll
    for (int n = 0; n < 4; ++n) {
      int chunk = w * 4 + n;
      int rga = m0 + arow[n];
      if (rga > M - 1) rga = M - 1;  // duplicate last row; stores are masked
      ASYNC_CP16(&A[(size_t)rga * K + kt + akb[n] * 8], &As[chunk * 512]);
    }
#pragma unroll
    for (int n = 0; n < 8; ++n) {
      int chunk = w * 8 + n;
      int rgb = n0 + brow[n];  // N is a multiple of 256
      ASYNC_CP16(&Bw[(size_t)rgb * K + kt + bkb[n] * 8], &Bs[chunk * 512]);
    }
    __syncthreads();  // drains vmcnt -> LDS tiles complete

#pragma unroll
    for (int s = 0; s < 2; ++s) {
      f16x8 af[4], bf[8];
#pragma unroll
      for (int t = 0; t < 4; ++t)
        af[t] = *reinterpret_cast<const f16x8*>(
            &As[(((s * 4 + quad) << 7) + wm + t * 16 + lr) * 8]);
#pragma unroll
      for (int t = 0; t < 8; ++t)
        bf[t] = *reinterpret_cast<const f16x8*>(
            &Bs[(((s * 4 + quad) << 8) + wn + t * 16 + lr) * 8]);
#pragma unroll
      for (int i = 0; i < 4; ++i)
#pragma unroll
        for (int j = 0; j < 8; ++j)
          acc[i][j] = __builtin_amdgcn_mfma_f32_16x16x32_f16(af[i], bf[j],
                                                             acc[i][j], 0, 0, 0);
    }
    __syncthreads();  // all waves done reading LDS before next stage
  }

  float bv[8];
#pragma unroll
  for (int tn = 0; tn < 8; ++tn) bv[tn] = bias[n0 + wn + tn * 16 + lr];
#pragma unroll
  for (int ti = 0; ti < 4; ++ti) {
#pragma unroll
    for (int tj = 0; tj < 8; ++tj) {
#pragma unroll
      for (int r = 0; r < 4; ++r) {
        int row = m0 + wm + ti * 16 + quad * 4 + r;
        if (row < M) {
          int col = n0 + wn + tj * 16 + lr;
          Cm[(size_t)row * N + col] = (OutT)(acc[ti][tj][r] + bv[tj]);
        }
      }
    }
  }
}

// ----------------------------------- v7: 256^2 8-phase GEMM (QKV path)
// Exact m201 stage-slot schedule: 2 K-tiles per 8-phase iteration, ONE
// half-tile staged per phase, vmcnt(4) gates at phases 4 and 8 only.
// Slot order (iteration over tiles t0=2*itr [buf0], t0+1 [buf1]):
//   P1: Ah0(t0+1)->buf1   P2: Ah1(t0+1)->buf1
//   P3: Bh0(t0+2)->buf0   P4: Bh1(t0+2)->buf0 ; gate vmcnt(4)
//   P5: Ah0(t0+2)->buf0   P6: Ah1(t0+2)->buf0
//   P7: Bh0(t0+3)->buf1   P8: Bh1(t0+3)->buf1 ; gate vmcnt(4)
// At each gate exactly the 2 just-staged B half-tiles (4 loads) remain in
// flight, so the next-consumed tile is guaranteed landed; every half-tile
// has >=2.5 phases between its last stage and its gate (covers HBM).
// Legality (region free times, hand-checked): A(buf hf) read at P1/P3 of its
// half -> free after P3-end barrier; B(buf hf) read at P1/P2 -> free after
// P2-end barrier. All slots above respect these. Tail: stages guarded by
// t<NT; gates degrade to vmcnt(0) when their trailing stages were skipped.
// v6 failure mode fixed here: A(t+1) was staged only 2.5 phases before a
// per-tile gate with no B-stage separation -> exposed HBM latency each tile.
template <typename OutT>
__global__ __launch_bounds__(512, 2) void gemm256_8ph(
    const f16* __restrict__ A, const f16* __restrict__ Bw,
    const float* __restrict__ bias, OutT* __restrict__ Cm,
    int M, int N, int K) {
  constexpr int HALF = 8192;      // f16 per half-tile (128 rows x 64 k)
  constexpr int ABUF = 2 * HALF;  // 16384 f16
  constexpr int BUF = 2 * ABUF;   // 32768 f16: [A h0|A h1|B h0|B h1]
  __shared__ __align__(16) f16 sm[2 * BUF];  // 128 KB

  const int tid = threadIdx.x;
  const int w = tid >> 6;
  const int lane = tid & 63;
  const int lr = lane & 15;
  const int quad = lane >> 4;
  const int wr = w >> 2;   // 0..1 : which 128-row half this wave computes
  const int wc = w & 3;    // 0..3 : which 64-col quarter
  const int gx = gridDim.x;
  const int sw = xcd_swizzle(blockIdx.y * gx + blockIdx.x, gx * gridDim.y);
  const int m0 = (sw / gx) * 256;
  const int n0 = (sw % gx) * 256;
  const int NT = K >> 6;   // 24 for K=1536 (even)

  // Staging descriptors. Each half-tile = 1024 16B-blocks; thread covers
  // block idx = tid and tid+512. idx -> kb = idx>>7 (k-group), r = idx&127.
  const f16* aptr[2][2];  // [half][n]
  const f16* bptr[2][2];
  int dstoff0 = tid * 8;
  int dstoff1 = (tid + 512) * 8;
#pragma unroll
  for (int h = 0; h < 2; ++h) {
#pragma unroll
    for (int n = 0; n < 2; ++n) {
      int idx = n * 512 + tid;
      int kb = idx >> 7, r = idx & 127;
      int ra = m0 + h * 128 + r;
      if (ra > M - 1) ra = M - 1;  // duplicate last rows; stores masked
      aptr[h][n] = A + (size_t)ra * K + kb * 8;
      bptr[h][n] = Bw + (size_t)(n0 + h * 128 + r) * K + kb * 8;  // N%256==0
    }
  }

  auto stageA = [&](int t, int h, int q) {
    f16* d = &sm[q * BUF + h * HALF];
    ASYNC_CP16(aptr[h][0] + t * 64, &d[dstoff0]);
    ASYNC_CP16(aptr[h][1] + t * 64, &d[dstoff1]);
  };
  auto stageB = [&](int t, int h, int q) {
    f16* d = &sm[q * BUF + ABUF + h * HALF];
    ASYNC_CP16(bptr[h][0] + t * 64, &d[dstoff0]);
    ASYNC_CP16(bptr[h][1] + t * 64, &d[dstoff1]);
  };

  f32x4 acc[8][4];
#pragma unroll
  for (int i = 0; i < 8; ++i)
#pragma unroll
    for (int j = 0; j < 4; ++j)
#pragma unroll
      for (int c = 0; c < 4; ++c) acc[i][j][c] = 0.0f;

  const int bRow0 = (wc & 1) * 64;  // col offset within B half-tile

  // Prologue: tile0 (4 halves) + B(1) halves = 12 loads; vmcnt(4) leaves
  // B(1)'s 4 in flight and guarantees tile0 landed. A(1) comes at P1/P2.
  stageA(0, 0, 0);
  stageA(0, 1, 0);
  stageB(0, 0, 0);
  stageB(0, 1, 0);
  stageB(1, 0, 1);
  stageB(1, 1, 1);
  asm volatile("s_waitcnt vmcnt(4)" ::: "memory");
  __builtin_amdgcn_s_barrier();

  const int NIT = NT >> 1;
  for (int itr = 0; itr < NIT; ++itr) {
    const int t0 = itr * 2;
#pragma unroll
    for (int hf = 0; hf < 2; ++hf) {
      const int tcur = t0 + hf;      // consumed tile, buffer = hf
      const int ta = tcur + 1;       // A prefetch target -> buf hf^1
      const int tb = tcur + 2;       // B prefetch target -> buf hf
      const f16* Aq = &sm[hf * BUF + wr * HALF];
      const f16* Bq = &sm[hf * BUF + ABUF + (wc >> 1) * HALF];
      f16x8 af[4][2], bfA[2][2], bfB[2][2];

      // ---- P1: read A m0-3 + B n0-1; stage Ah0(ta)
#pragma unroll
      for (int i = 0; i < 4; ++i)
#pragma unroll
        for (int s = 0; s < 2; ++s)
          af[i][s] = *reinterpret_cast<const f16x8*>(
              &Aq[(((s * 4 + quad) << 7) + i * 16 + lr) * 8]);
#pragma unroll
      for (int j = 0; j < 2; ++j)
#pragma unroll
        for (int s = 0; s < 2; ++s)
          bfA[j][s] = *reinterpret_cast<const f16x8*>(
              &Bq[(((s * 4 + quad) << 7) + bRow0 + j * 16 + lr) * 8]);
      if (ta < NT) stageA(ta, 0, hf ^ 1);
      __builtin_amdgcn_s_barrier();
      asm volatile("s_waitcnt lgkmcnt(0)" ::: "memory");
      __builtin_amdgcn_s_setprio(1);
#pragma unroll
      for (int s = 0; s < 2; ++s)
#pragma unroll
        for (int i = 0; i < 4; ++i)
#pragma unroll
          for (int j = 0; j < 2; ++j)
            acc[i][j] = __builtin_amdgcn_mfma_f32_16x16x32_f16(
                af[i][s], bfA[j][s], acc[i][j], 0, 0, 0);
      __builtin_amdgcn_s_setprio(0);
      __builtin_amdgcn_s_barrier();

      // ---- P2: read B n2-3; stage Ah1(ta)
#pragma unroll
      for (int j = 0; j < 2; ++j)
#pragma unroll
        for (int s = 0; s < 2; ++s)
          bfB[j][s] = *reinterpret_cast<const f16x8*>(
              &Bq[(((s * 4 + quad) << 7) + bRow0 + (j + 2) * 16 + lr) * 8]);
      if (ta < NT) stageA(ta, 1, hf ^ 1);
      __builtin_amdgcn_s_barrier();
      asm volatile("s_waitcnt lgkmcnt(0)" ::: "memory");
      __builtin_amdgcn_s_setprio(1);
#pragma unroll
      for (int s = 0; s < 2; ++s)
#pragma unroll
        for (int i = 0; i < 4; ++i)
#pragma unroll
          for (int j = 0; j < 2; ++j)
            acc[i][j + 2] = __builtin_amdgcn_mfma_f32_16x16x32_f16(
                af[i][s], bfB[j][s], acc[i][j + 2], 0, 0, 0);
      __builtin_amdgcn_s_setprio(0);
      __builtin_amdgcn_s_barrier();

      // ---- P3: read A m4-7 (overwrite af); stage Bh0(tb)
#pragma unroll
      for (int i = 0; i < 4; ++i)
#pragma unroll
        for (int s = 0; s < 2; ++s)
          af[i][s] = *reinterpret_cast<const f16x8*>(
              &Aq[(((s * 4 + quad) << 7) + (i + 4) * 16 + lr) * 8]);
      if (tb < NT) stageB(tb, 0, hf);
      __builtin_amdgcn_s_barrier();
      asm volatile("s_waitcnt lgkmcnt(0)" ::: "memory");
      __builtin_amdgcn_s_setprio(1);
#pragma unroll
      for (int s = 0; s < 2; ++s)
#pragma unroll
        for (int i = 0; i < 4; ++i)
#pragma unroll
          for (int j = 0; j < 2; ++j)
            acc[i + 4][j + 2] = __builtin_amdgcn_mfma_f32_16x16x32_f16(
                af[i][s], bfB[j][s], acc[i + 4][j + 2], 0, 0, 0);
      __builtin_amdgcn_s_setprio(0);
      __builtin_amdgcn_s_barrier();

      // ---- P4: no reads (af from P3, bfA from P1); stage Bh1(tb); gate
      if (tb < NT) stageB(tb, 1, hf);
      __builtin_amdgcn_s_barrier();
      __builtin_amdgcn_s_setprio(1);
#pragma unroll
      for (int s = 0; s < 2; ++s)
#pragma unroll
        for (int i = 0; i < 4; ++i)
#pragma unroll
          for (int j = 0; j < 2; ++j)
            acc[i + 4][j] = __builtin_amdgcn_mfma_f32_16x16x32_f16(
                af[i][s], bfA[j][s], acc[i + 4][j], 0, 0, 0);
      __builtin_amdgcn_s_setprio(0);
      if (tb < NT)
        asm volatile("s_waitcnt vmcnt(4)" ::: "memory");
      else
        asm volatile("s_waitcnt vmcnt(0)" ::: "memory");
      __builtin_amdgcn_s_barrier();
    }
  }

  // Epilogue: C/D layout col = lane&15, row = quad*4+reg.
  float bv[4];
#pragma unroll
  for (int j = 0; j < 4; ++j) bv[j] = bias[n0 + wc * 64 + j * 16 + lr];
#pragma unroll
  for (int i = 0; i < 8; ++i) {
#pragma unroll
    for (int j = 0; j < 4; ++j) {
#pragma unroll
      for (int r = 0; r < 4; ++r) {
        int row = m0 + wr * 128 + i * 16 + quad * 4 + r;
        if (row < M) {
          int col = n0 + wc * 64 + j * 16 + lr;
          Cm[(size_t)row * N + col] = (OutT)(acc[i][j][r] + bv[j]);
        }
      }
    }
  }
}

// --------------------------------------------------------------------- RoPE
__global__ void rope_kernel(f16* __restrict__ qkv,
                            const float* __restrict__ pos) {
  int idx = blockIdx.x * blockDim.x + threadIdx.x;
  if (idx >= kM * kH * 32) return;
  int d = idx & 31;
  int rem = idx >> 5;
  int h = rem % kH;
  int bl = rem / kH;
  float p0 = pos[bl * 2 + 0];
  float p1 = pos[bl * 2 + 1];
  float f = exp2f(-(float)(d & 15) * (13.287712379549449f / 16.0f));
  float s0, c0, s1, c1;
  sincosf(p0 * f, &s0, &c0);
  sincosf(p1 * f, &s1, &c1);
  size_t base = (size_t)bl * kN3 + h * kD;
  {
    float t0 = (float)qkv[base + d];
    float t1 = (float)qkv[base + d + 32];
    qkv[base + d] = (f16)(t0 * c0 - t1 * s0);
    qkv[base + d + 32] = (f16)(t1 * c1 + t0 * s1);
  }
  {
    size_t kb = base + kC;
    float t0 = (float)qkv[kb + d];
    float t1 = (float)qkv[kb + d + 32];
    qkv[kb + d] = (f16)(t0 * c0 - t1 * s0);
    qkv[kb + d + 32] = (f16)(t1 * c1 + t0 * s1);
  }
}

// ----------------------------------------------------- MFMA flash attention
// (unchanged)
__global__ __launch_bounds__(256, 3) void attn_mfma(
    const f16* __restrict__ qkv, f16* __restrict__ attnout) {
  __shared__ __align__(16) f16 Ks[64 * 72];       // [key][d]
  __shared__ __align__(16) f16 Vts[64 * 72];      // [d][key]  (V transposed)
  __shared__ __align__(16) float Pl[4][32 * 68];  // per-wave [qrow][key] f32

  const int tid = threadIdx.x;
  const int w = tid >> 6;
  const int lane = tid & 63;
  const int lr = lane & 15;
  const int qd = lane >> 4;

  const int bid = blockIdx.x;
  const int xcd = bid & 7;
  const int rest = bid >> 3;
  const int qt = rest % kNQT;
  const int g = xcd + 8 * (rest / kNQT);
  const int h = g % kH;
  const int b = g / kH;
  const int q0 = qt * 128;

  f16x8 aq[2][2];
#pragma unroll
  for (int rt = 0; rt < 2; ++rt) {
    int qrow = q0 + w * 32 + rt * 16 + lr;
    if (qrow > kL - 1) qrow = kL - 1;
    const f16* qp = qkv + (size_t)(b * kL + qrow) * kN3 + h * kD;
#pragma unroll
    for (int ks = 0; ks < 2; ++ks)
      aq[rt][ks] =
          *reinterpret_cast<const f16x8*>(qp + ks * 32 + qd * 8);
  }

  const int kkey0 = tid >> 3, kdc = tid & 7;
  const int kkey1 = (tid + 256) >> 3;
  const int vkey0 = (tid & 31) * 2;
  const int vd0 = (tid >> 5) * 8;

  f16x8 kpre0, kpre1, vpre0, vpre1;
  auto prefetch = [&](int kt0) {
    int kg0 = kt0 + kkey0;
    if (kg0 > kL - 1) kg0 = kL - 1;
    kpre0 = *reinterpret_cast<const f16x8*>(
        qkv + (size_t)(b * kL + kg0) * kN3 + kC + h * kD + kdc * 8);
    int kg1 = kt0 + kkey1;
    if (kg1 > kL - 1) kg1 = kL - 1;
    kpre1 = *reinterpret_cast<const f16x8*>(
        qkv + (size_t)(b * kL + kg1) * kN3 + kC + h * kD + kdc * 8);
    int vg0 = kt0 + vkey0;
    if (vg0 > kL - 1) vg0 = kL - 1;
    vpre0 = *reinterpret_cast<const f16x8*>(
        qkv + (size_t)(b * kL + vg0) * kN3 + 2 * kC + h * kD + vd0);
    int vg1 = kt0 + vkey0 + 1;
    if (vg1 > kL - 1) vg1 = kL - 1;
    vpre1 = *reinterpret_cast<const f16x8*>(
        qkv + (size_t)(b * kL + vg1) * kN3 + 2 * kC + h * kD + vd0);
  };
  prefetch(0);

  f32x4 o_acc[2][4];
#pragma unroll
  for (int rt = 0; rt < 2; ++rt)
#pragma unroll
    for (int nt = 0; nt < 4; ++nt)
#pragma unroll
      for (int r = 0; r < 4; ++r) o_acc[rt][nt][r] = 0.0f;
  float lsum[2][4] = {{0.f, 0.f, 0.f, 0.f}, {0.f, 0.f, 0.f, 0.f}};

  for (int it = 0; it < kNKT; ++it) {
    const int kt0 = it * 64;
    __syncthreads();

    *reinterpret_cast<f16x8*>(&Ks[kkey0 * 72 + kdc * 8]) = kpre0;
    *reinterpret_cast<f16x8*>(&Ks[kkey1 * 72 + kdc * 8]) = kpre1;
#pragma unroll
    for (int i = 0; i < 8; ++i) {
      f16x2 pr;
      pr[0] = vpre0[i];
      pr[1] = vpre1[i];
      *reinterpret_cast<f16x2*>(&Vts[(vd0 + i) * 72 + vkey0]) = pr;
    }
    prefetch((it < kNKT - 1) ? (it + 1) * 64 : it * 64);
    __syncthreads();

    f32x4 s_acc[2][4];
#pragma unroll
    for (int rt = 0; rt < 2; ++rt)
#pragma unroll
      for (int t = 0; t < 4; ++t)
#pragma unroll
        for (int r = 0; r < 4; ++r) s_acc[rt][t][r] = 0.0f;
#pragma unroll
    for (int ks = 0; ks < 2; ++ks) {
#pragma unroll
      for (int t = 0; t < 4; ++t) {
        f16x8 bk = *reinterpret_cast<const f16x8*>(
            &Ks[(t * 16 + lr) * 72 + ks * 32 + qd * 8]);
        s_acc[0][t] = __builtin_amdgcn_mfma_f32_16x16x32_f16(
            aq[0][ks], bk, s_acc[0][t], 0, 0, 0);
        s_acc[1][t] = __builtin_amdgcn_mfma_f32_16x16x32_f16(
            aq[1][ks], bk, s_acc[1][t], 0, 0, 0);
      }
    }

#pragma unroll
    for (int rt = 0; rt < 2; ++rt) {
#pragma unroll
      for (int t = 0; t < 4; ++t) {
        const bool valid = (kt0 + t * 16 + lr) < kL;
#pragma unroll
        for (int r = 0; r < 4; ++r) {
          float p = valid ? __expf(s_acc[rt][t][r] * 0.125f) : 0.0f;
          lsum[rt][r] += p;
          Pl[w][(rt * 16 + qd * 4 + r) * 68 + t * 16 + lr] = p;
        }
      }
    }

#pragma unroll
    for (int ks = 0; ks < 2; ++ks) {
      f16x8 ap[2];
#pragma unroll
      for (int rt = 0; rt < 2; ++rt) {
        float4 pa = *reinterpret_cast<const float4*>(
            &Pl[w][(rt * 16 + lr) * 68 + ks * 32 + qd * 8]);
        float4 pb = *reinterpret_cast<const float4*>(
            &Pl[w][(rt * 16 + lr) * 68 + ks * 32 + qd * 8 + 4]);
        ap[rt][0] = (f16)pa.x;
        ap[rt][1] = (f16)pa.y;
        ap[rt][2] = (f16)pa.z;
        ap[rt][3] = (f16)pa.w;
        ap[rt][4] = (f16)pb.x;
        ap[rt][5] = (f16)pb.y;
        ap[rt][6] = (f16)pb.z;
        ap[rt][7] = (f16)pb.w;
      }
#pragma unroll
      for (int nt = 0; nt < 4; ++nt) {
        f16x8 bv = *reinterpret_cast<const f16x8*>(
            &Vts[(nt * 16 + lr) * 72 + ks * 32 + qd * 8]);
        o_acc[0][nt] = __builtin_amdgcn_mfma_f32_16x16x32_f16(
            ap[0], bv, o_acc[0][nt], 0, 0, 0);
        o_acc[1][nt] = __builtin_amdgcn_mfma_f32_16x16x32_f16(
            ap[1], bv, o_acc[1][nt], 0, 0, 0);
      }
    }
  }

#pragma unroll
  for (int rt = 0; rt < 2; ++rt)
#pragma unroll
    for (int r = 0; r < 4; ++r) {
#pragma unroll
      for (int m = 1; m < 16; m <<= 1)
        lsum[rt][r] += __shfl_xor(lsum[rt][r], m, 64);
    }

#pragma unroll
  for (int rt = 0; rt < 2; ++rt) {
#pragma unroll
    for (int nt = 0; nt < 4; ++nt) {
#pragma unroll
      for (int r = 0; r < 4; ++r) {
        int qr = q0 + w * 32 + rt * 16 + qd * 4 + r;
        if (qr < kL) {
          attnout[(size_t)(b * kL + qr) * kC + h * kD + nt * 16 + lr] =
              (f16)(o_acc[rt][nt][r] / lsum[rt][r]);
        }
      }
    }
  }
}

}  // namespace

extern "C" void kernel_launch(void* const* d_in, const int* in_sizes, int n_in,
                              void* d_out, int out_size, void* d_ws,
                              size_t ws_size, hipStream_t stream) {
  const float* x = (const float*)d_in[0];
  const float* pos = (const float*)d_in[1];
  const float* w_qkv = (const float*)d_in[2];
  const float* q_bias = (const float*)d_in[3];
  const float* v_bias = (const float*)d_in[4];
  const float* w_o = (const float*)d_in[5];
  const float* b_o = (const float*)d_in[6];
  float* out = (float*)d_out;

  f16* qkv16 = (f16*)d_ws;                       // kM*kN3
  f16* x16 = qkv16 + (size_t)kM * kN3;           // kM*kC
  f16* wqkv16 = x16 + (size_t)kM * kC;           // kN3*kC
  f16* wo16 = wqkv16 + (size_t)kN3 * kC;         // kC*kC
  f16* ao16 = wo16 + (size_t)kC * kC;            // kM*kC
  float* bias_full = (float*)(ao16 + (size_t)kM * kC);  // kN3 floats

  cvt_f32_f16<<<(kM * kC / 4 + 255) / 256, 256, 0, stream>>>(x, x16, kM * kC);
  cvt_f32_f16<<<(kN3 * kC / 4 + 255) / 256, 256, 0, stream>>>(w_qkv, wqkv16,
                                                              kN3 * kC);
  cvt_f32_f16<<<(kC * kC / 4 + 255) / 256, 256, 0, stream>>>(w_o, wo16,
                                                             kC * kC);
  build_bias_kernel<<<(kN3 + 255) / 256, 256, 0, stream>>>(q_bias, v_bias,
                                                           bias_full);
  gemm256_8ph<f16><<<dim3(kN3 / 256, (kM + 255) / 256), 512, 0, stream>>>(
      x16, wqkv16, bias_full, qkv16, kM, kN3, kC);
  rope_kernel<<<(kM * kH * 32 + 255) / 256, 256, 0, stream>>>(qkv16, pos);
  attn_mfma<<<dim3(kNQT * kH * kB), 256, 0, stream>>>(qkv16, ao16);
  gemm_f16<float><<<dim3(kC / 256, (kM + 127) / 128), 256, 0, stream>>>(
      ao16, wo16, b_o, out, kM, kC, kC);
}

// Round 4
// 402.374 us; speedup vs baseline: 1.0341x; 1.0341x over previous
//
#include <hip/hip_runtime.h>
#include <cmath>

typedef _Float16 f16;
typedef _Float16 f16x2 __attribute__((ext_vector_type(2)));
typedef _Float16 f16x4 __attribute__((ext_vector_type(4)));
typedef _Float16 f16x8 __attribute__((ext_vector_type(8)));
typedef float f32x4 __attribute__((ext_vector_type(4)));

namespace {

constexpr int kB = 8;
constexpr int kL = 680;
constexpr int kH = 24;
constexpr int kD = 64;
constexpr int kC = 1536;          // kH * kD
constexpr int kM = kB * kL;       // 5440
constexpr int kN3 = 3 * kC;       // 4608
constexpr int kNKT = 11;          // ceil(680/64)
constexpr int kNQT = 6;           // ceil(680/128)

#define ASYNC_CP16(gp, lp)                                          \
  __builtin_amdgcn_global_load_lds(                                 \
      (const __attribute__((address_space(1))) unsigned int*)(gp),  \
      (__attribute__((address_space(3))) unsigned int*)(lp), 16, 0, 0)

// Bijective XCD swizzle (m204): same-XCD blocks get contiguous linear ids
// so panel reuse lands in the XCD-private 4MB L2. Works for any nwg.
__device__ inline int xcd_swizzle(int bid, int nwg) {
  int q = nwg >> 3, r = nwg & 7;
  int x = bid & 7, idx = bid >> 3;
  return (x < r ? x * (q + 1) : r * (q + 1) + (x - r) * q) + idx;
}

// ------------------------------------------------------------- fp32 -> fp16
__global__ void cvt_f32_f16(const float* __restrict__ in,
                            f16* __restrict__ out, int n) {
  int i = (blockIdx.x * blockDim.x + threadIdx.x) * 4;
  if (i >= n) return;  // n is a multiple of 4 for all our arrays
  float4 v = *reinterpret_cast<const float4*>(&in[i]);
  f16x4 o;
  o[0] = (f16)v.x;
  o[1] = (f16)v.y;
  o[2] = (f16)v.z;
  o[3] = (f16)v.w;
  *reinterpret_cast<f16x4*>(&out[i]) = o;
}

// ---------------------------------------------------------------- bias build
__global__ void build_bias_kernel(const float* __restrict__ qb,
                                  const float* __restrict__ vb,
                                  float* __restrict__ bias) {
  int i = blockIdx.x * blockDim.x + threadIdx.x;
  if (i >= kN3) return;
  float v = 0.0f;
  if (i < kC) v = qb[i];
  else if (i >= 2 * kC) v = vb[i - 2 * kC];
  bias[i] = v;
}

// ----------------------------------- 256^2 8-phase GEMM (both GEMMs)
// m201 stage-slot schedule: 2 K-tiles per 8-phase iteration, ONE half-tile
// staged per phase, vmcnt(4) gates at phases 4 and 8 only. Measured (r3):
// 149.8 us on QKV (M=5440,N=4608,K=1536), MfmaUtil 21.8, bank-conflict 0.
// Now also used for proj (N=1536 -> grid 132 blocks): under-subscribes CUs
// but per-block time beats the old 2-barrier vmcnt(0) structure (~110us).
template <typename OutT>
__global__ __launch_bounds__(512, 2) void gemm256_8ph(
    const f16* __restrict__ A, const f16* __restrict__ Bw,
    const float* __restrict__ bias, OutT* __restrict__ Cm,
    int M, int N, int K) {
  constexpr int HALF = 8192;      // f16 per half-tile (128 rows x 64 k)
  constexpr int ABUF = 2 * HALF;  // 16384 f16
  constexpr int BUF = 2 * ABUF;   // 32768 f16: [A h0|A h1|B h0|B h1]
  __shared__ __align__(16) f16 sm[2 * BUF];  // 128 KB

  const int tid = threadIdx.x;
  const int w = tid >> 6;
  const int lane = tid & 63;
  const int lr = lane & 15;
  const int quad = lane >> 4;
  const int wr = w >> 2;   // 0..1 : which 128-row half this wave computes
  const int wc = w & 3;    // 0..3 : which 64-col quarter
  const int gx = gridDim.x;
  const int sw = xcd_swizzle(blockIdx.y * gx + blockIdx.x, gx * gridDim.y);
  const int m0 = (sw / gx) * 256;
  const int n0 = (sw % gx) * 256;
  const int NT = K >> 6;   // 24 for K=1536 (even)

  // Staging descriptors. Each half-tile = 1024 16B-blocks; thread covers
  // block idx = tid and tid+512. idx -> kb = idx>>7 (k-group), r = idx&127.
  const f16* aptr[2][2];  // [half][n]
  const f16* bptr[2][2];
  int dstoff0 = tid * 8;
  int dstoff1 = (tid + 512) * 8;
#pragma unroll
  for (int h = 0; h < 2; ++h) {
#pragma unroll
    for (int n = 0; n < 2; ++n) {
      int idx = n * 512 + tid;
      int kb = idx >> 7, r = idx & 127;
      int ra = m0 + h * 128 + r;
      if (ra > M - 1) ra = M - 1;  // duplicate last rows; stores masked
      aptr[h][n] = A + (size_t)ra * K + kb * 8;
      bptr[h][n] = Bw + (size_t)(n0 + h * 128 + r) * K + kb * 8;  // N%256==0
    }
  }

  auto stageA = [&](int t, int h, int q) {
    f16* d = &sm[q * BUF + h * HALF];
    ASYNC_CP16(aptr[h][0] + t * 64, &d[dstoff0]);
    ASYNC_CP16(aptr[h][1] + t * 64, &d[dstoff1]);
  };
  auto stageB = [&](int t, int h, int q) {
    f16* d = &sm[q * BUF + ABUF + h * HALF];
    ASYNC_CP16(bptr[h][0] + t * 64, &d[dstoff0]);
    ASYNC_CP16(bptr[h][1] + t * 64, &d[dstoff1]);
  };

  f32x4 acc[8][4];
#pragma unroll
  for (int i = 0; i < 8; ++i)
#pragma unroll
    for (int j = 0; j < 4; ++j)
#pragma unroll
      for (int c = 0; c < 4; ++c) acc[i][j][c] = 0.0f;

  const int bRow0 = (wc & 1) * 64;  // col offset within B half-tile

  // Prologue: tile0 (4 halves) + B(1) halves = 12 loads; vmcnt(4) leaves
  // B(1)'s 4 in flight and guarantees tile0 landed. A(1) comes at P1/P2.
  stageA(0, 0, 0);
  stageA(0, 1, 0);
  stageB(0, 0, 0);
  stageB(0, 1, 0);
  stageB(1, 0, 1);
  stageB(1, 1, 1);
  asm volatile("s_waitcnt vmcnt(4)" ::: "memory");
  __builtin_amdgcn_s_barrier();

  const int NIT = NT >> 1;
  for (int itr = 0; itr < NIT; ++itr) {
    const int t0 = itr * 2;
#pragma unroll
    for (int hf = 0; hf < 2; ++hf) {
      const int tcur = t0 + hf;      // consumed tile, buffer = hf
      const int ta = tcur + 1;       // A prefetch target -> buf hf^1
      const int tb = tcur + 2;       // B prefetch target -> buf hf
      const f16* Aq = &sm[hf * BUF + wr * HALF];
      const f16* Bq = &sm[hf * BUF + ABUF + (wc >> 1) * HALF];
      f16x8 af[4][2], bfA[2][2], bfB[2][2];

      // ---- P1: read A m0-3 + B n0-1; stage Ah0(ta)
#pragma unroll
      for (int i = 0; i < 4; ++i)
#pragma unroll
        for (int s = 0; s < 2; ++s)
          af[i][s] = *reinterpret_cast<const f16x8*>(
              &Aq[(((s * 4 + quad) << 7) + i * 16 + lr) * 8]);
#pragma unroll
      for (int j = 0; j < 2; ++j)
#pragma unroll
        for (int s = 0; s < 2; ++s)
          bfA[j][s] = *reinterpret_cast<const f16x8*>(
              &Bq[(((s * 4 + quad) << 7) + bRow0 + j * 16 + lr) * 8]);
      if (ta < NT) stageA(ta, 0, hf ^ 1);
      __builtin_amdgcn_s_barrier();
      asm volatile("s_waitcnt lgkmcnt(0)" ::: "memory");
      __builtin_amdgcn_s_setprio(1);
#pragma unroll
      for (int s = 0; s < 2; ++s)
#pragma unroll
        for (int i = 0; i < 4; ++i)
#pragma unroll
          for (int j = 0; j < 2; ++j)
            acc[i][j] = __builtin_amdgcn_mfma_f32_16x16x32_f16(
                af[i][s], bfA[j][s], acc[i][j], 0, 0, 0);
      __builtin_amdgcn_s_setprio(0);
      __builtin_amdgcn_s_barrier();

      // ---- P2: read B n2-3; stage Ah1(ta)
#pragma unroll
      for (int j = 0; j < 2; ++j)
#pragma unroll
        for (int s = 0; s < 2; ++s)
          bfB[j][s] = *reinterpret_cast<const f16x8*>(
              &Bq[(((s * 4 + quad) << 7) + bRow0 + (j + 2) * 16 + lr) * 8]);
      if (ta < NT) stageA(ta, 1, hf ^ 1);
      __builtin_amdgcn_s_barrier();
      asm volatile("s_waitcnt lgkmcnt(0)" ::: "memory");
      __builtin_amdgcn_s_setprio(1);
#pragma unroll
      for (int s = 0; s < 2; ++s)
#pragma unroll
        for (int i = 0; i < 4; ++i)
#pragma unroll
          for (int j = 0; j < 2; ++j)
            acc[i][j + 2] = __builtin_amdgcn_mfma_f32_16x16x32_f16(
                af[i][s], bfB[j][s], acc[i][j + 2], 0, 0, 0);
      __builtin_amdgcn_s_setprio(0);
      __builtin_amdgcn_s_barrier();

      // ---- P3: read A m4-7 (overwrite af); stage Bh0(tb)
#pragma unroll
      for (int i = 0; i < 4; ++i)
#pragma unroll
        for (int s = 0; s < 2; ++s)
          af[i][s] = *reinterpret_cast<const f16x8*>(
              &Aq[(((s * 4 + quad) << 7) + (i + 4) * 16 + lr) * 8]);
      if (tb < NT) stageB(tb, 0, hf);
      __builtin_amdgcn_s_barrier();
      asm volatile("s_waitcnt lgkmcnt(0)" ::: "memory");
      __builtin_amdgcn_s_setprio(1);
#pragma unroll
      for (int s = 0; s < 2; ++s)
#pragma unroll
        for (int i = 0; i < 4; ++i)
#pragma unroll
          for (int j = 0; j < 2; ++j)
            acc[i + 4][j + 2] = __builtin_amdgcn_mfma_f32_16x16x32_f16(
                af[i][s], bfB[j][s], acc[i + 4][j + 2], 0, 0, 0);
      __builtin_amdgcn_s_setprio(0);
      __builtin_amdgcn_s_barrier();

      // ---- P4: no reads (af from P3, bfA from P1); stage Bh1(tb); gate
      if (tb < NT) stageB(tb, 1, hf);
      __builtin_amdgcn_s_barrier();
      __builtin_amdgcn_s_setprio(1);
#pragma unroll
      for (int s = 0; s < 2; ++s)
#pragma unroll
        for (int i = 0; i < 4; ++i)
#pragma unroll
          for (int j = 0; j < 2; ++j)
            acc[i + 4][j] = __builtin_amdgcn_mfma_f32_16x16x32_f16(
                af[i][s], bfA[j][s], acc[i + 4][j], 0, 0, 0);
      __builtin_amdgcn_s_setprio(0);
      if (tb < NT)
        asm volatile("s_waitcnt vmcnt(4)" ::: "memory");
      else
        asm volatile("s_waitcnt vmcnt(0)" ::: "memory");
      __builtin_amdgcn_s_barrier();
    }
  }

  // Epilogue: C/D layout col = lane&15, row = quad*4+reg.
  float bv[4];
#pragma unroll
  for (int j = 0; j < 4; ++j) bv[j] = bias[n0 + wc * 64 + j * 16 + lr];
#pragma unroll
  for (int i = 0; i < 8; ++i) {
#pragma unroll
    for (int j = 0; j < 4; ++j) {
#pragma unroll
      for (int r = 0; r < 4; ++r) {
        int row = m0 + wr * 128 + i * 16 + quad * 4 + r;
        if (row < M) {
          int col = n0 + wc * 64 + j * 16 + lr;
          Cm[(size_t)row * N + col] = (OutT)(acc[i][j][r] + bv[j]);
        }
      }
    }
  }
}

// --------------------------------------------------------------------- RoPE
__global__ void rope_kernel(f16* __restrict__ qkv,
                            const float* __restrict__ pos) {
  int idx = blockIdx.x * blockDim.x + threadIdx.x;
  if (idx >= kM * kH * 32) return;
  int d = idx & 31;
  int rem = idx >> 5;
  int h = rem % kH;
  int bl = rem / kH;
  float p0 = pos[bl * 2 + 0];
  float p1 = pos[bl * 2 + 1];
  float f = exp2f(-(float)(d & 15) * (13.287712379549449f / 16.0f));
  float s0, c0, s1, c1;
  sincosf(p0 * f, &s0, &c0);
  sincosf(p1 * f, &s1, &c1);
  size_t base = (size_t)bl * kN3 + h * kD;
  {
    float t0 = (float)qkv[base + d];
    float t1 = (float)qkv[base + d + 32];
    qkv[base + d] = (f16)(t0 * c0 - t1 * s0);
    qkv[base + d + 32] = (f16)(t1 * c1 + t0 * s1);
  }
  {
    size_t kb = base + kC;
    float t0 = (float)qkv[kb + d];
    float t1 = (float)qkv[kb + d + 32];
    qkv[kb + d] = (f16)(t0 * c0 - t1 * s0);
    qkv[kb + d + 32] = (f16)(t1 * c1 + t0 * s1);
  }
}

// ----------------------------------------------------- MFMA flash attention
// v8: P staged in LDS as f16 (was f32). The PV MFMA consumed f16 P already,
// so numerics are unchanged; Pl read+write LDS traffic halves (attn is
// LDS-BW-dominated: ~3000 cyc LDS vs ~465 cyc MFMA per CU-tile), and LDS
// drops 55 -> 36 KB (4th resident block possible if VGPRs permit).
// Pl stride 72 f16 = 144 B rows: 16B-aligned for b128 reads; within any
// 16-consecutive-lane group reads are <=2-way (free, m136).
__global__ __launch_bounds__(256, 3) void attn_mfma(
    const f16* __restrict__ qkv, f16* __restrict__ attnout) {
  __shared__ __align__(16) f16 Ks[64 * 72];       // [key][d]
  __shared__ __align__(16) f16 Vts[64 * 72];      // [d][key]  (V transposed)
  __shared__ __align__(16) f16 Pl[4][32 * 72];    // per-wave [qrow][key] f16

  const int tid = threadIdx.x;
  const int w = tid >> 6;
  const int lane = tid & 63;
  const int lr = lane & 15;
  const int qd = lane >> 4;

  const int bid = blockIdx.x;
  const int xcd = bid & 7;
  const int rest = bid >> 3;
  const int qt = rest % kNQT;
  const int g = xcd + 8 * (rest / kNQT);
  const int h = g % kH;
  const int b = g / kH;
  const int q0 = qt * 128;

  f16x8 aq[2][2];
#pragma unroll
  for (int rt = 0; rt < 2; ++rt) {
    int qrow = q0 + w * 32 + rt * 16 + lr;
    if (qrow > kL - 1) qrow = kL - 1;
    const f16* qp = qkv + (size_t)(b * kL + qrow) * kN3 + h * kD;
#pragma unroll
    for (int ks = 0; ks < 2; ++ks)
      aq[rt][ks] =
          *reinterpret_cast<const f16x8*>(qp + ks * 32 + qd * 8);
  }

  const int kkey0 = tid >> 3, kdc = tid & 7;
  const int kkey1 = (tid + 256) >> 3;
  const int vkey0 = (tid & 31) * 2;
  const int vd0 = (tid >> 5) * 8;

  f16x8 kpre0, kpre1, vpre0, vpre1;
  auto prefetch = [&](int kt0) {
    int kg0 = kt0 + kkey0;
    if (kg0 > kL - 1) kg0 = kL - 1;
    kpre0 = *reinterpret_cast<const f16x8*>(
        qkv + (size_t)(b * kL + kg0) * kN3 + kC + h * kD + kdc * 8);
    int kg1 = kt0 + kkey1;
    if (kg1 > kL - 1) kg1 = kL - 1;
    kpre1 = *reinterpret_cast<const f16x8*>(
        qkv + (size_t)(b * kL + kg1) * kN3 + kC + h * kD + kdc * 8);
    int vg0 = kt0 + vkey0;
    if (vg0 > kL - 1) vg0 = kL - 1;
    vpre0 = *reinterpret_cast<const f16x8*>(
        qkv + (size_t)(b * kL + vg0) * kN3 + 2 * kC + h * kD + vd0);
    int vg1 = kt0 + vkey0 + 1;
    if (vg1 > kL - 1) vg1 = kL - 1;
    vpre1 = *reinterpret_cast<const f16x8*>(
        qkv + (size_t)(b * kL + vg1) * kN3 + 2 * kC + h * kD + vd0);
  };
  prefetch(0);

  f32x4 o_acc[2][4];
#pragma unroll
  for (int rt = 0; rt < 2; ++rt)
#pragma unroll
    for (int nt = 0; nt < 4; ++nt)
#pragma unroll
      for (int r = 0; r < 4; ++r) o_acc[rt][nt][r] = 0.0f;
  float lsum[2][4] = {{0.f, 0.f, 0.f, 0.f}, {0.f, 0.f, 0.f, 0.f}};

  for (int it = 0; it < kNKT; ++it) {
    const int kt0 = it * 64;
    __syncthreads();

    *reinterpret_cast<f16x8*>(&Ks[kkey0 * 72 + kdc * 8]) = kpre0;
    *reinterpret_cast<f16x8*>(&Ks[kkey1 * 72 + kdc * 8]) = kpre1;
#pragma unroll
    for (int i = 0; i < 8; ++i) {
      f16x2 pr;
      pr[0] = vpre0[i];
      pr[1] = vpre1[i];
      *reinterpret_cast<f16x2*>(&Vts[(vd0 + i) * 72 + vkey0]) = pr;
    }
    prefetch((it < kNKT - 1) ? (it + 1) * 64 : it * 64);
    __syncthreads();

    f32x4 s_acc[2][4];
#pragma unroll
    for (int rt = 0; rt < 2; ++rt)
#pragma unroll
      for (int t = 0; t < 4; ++t)
#pragma unroll
        for (int r = 0; r < 4; ++r) s_acc[rt][t][r] = 0.0f;
#pragma unroll
    for (int ks = 0; ks < 2; ++ks) {
#pragma unroll
      for (int t = 0; t < 4; ++t) {
        f16x8 bk = *reinterpret_cast<const f16x8*>(
            &Ks[(t * 16 + lr) * 72 + ks * 32 + qd * 8]);
        s_acc[0][t] = __builtin_amdgcn_mfma_f32_16x16x32_f16(
            aq[0][ks], bk, s_acc[0][t], 0, 0, 0);
        s_acc[1][t] = __builtin_amdgcn_mfma_f32_16x16x32_f16(
            aq[1][ks], bk, s_acc[1][t], 0, 0, 0);
      }
    }

#pragma unroll
    for (int rt = 0; rt < 2; ++rt) {
#pragma unroll
      for (int t = 0; t < 4; ++t) {
        const bool valid = (kt0 + t * 16 + lr) < kL;
#pragma unroll
        for (int r = 0; r < 4; ++r) {
          float p = valid ? __expf(s_acc[rt][t][r] * 0.125f) : 0.0f;
          lsum[rt][r] += p;
          Pl[w][(rt * 16 + qd * 4 + r) * 72 + t * 16 + lr] = (f16)p;
        }
      }
    }

#pragma unroll
    for (int ks = 0; ks < 2; ++ks) {
      f16x8 ap[2];
#pragma unroll
      for (int rt = 0; rt < 2; ++rt)
        ap[rt] = *reinterpret_cast<const f16x8*>(
            &Pl[w][(rt * 16 + lr) * 72 + ks * 32 + qd * 8]);
#pragma unroll
      for (int nt = 0; nt < 4; ++nt) {
        f16x8 bv = *reinterpret_cast<const f16x8*>(
            &Vts[(nt * 16 + lr) * 72 + ks * 32 + qd * 8]);
        o_acc[0][nt] = __builtin_amdgcn_mfma_f32_16x16x32_f16(
            ap[0], bv, o_acc[0][nt], 0, 0, 0);
        o_acc[1][nt] = __builtin_amdgcn_mfma_f32_16x16x32_f16(
            ap[1], bv, o_acc[1][nt], 0, 0, 0);
      }
    }
  }

#pragma unroll
  for (int rt = 0; rt < 2; ++rt)
#pragma unroll
    for (int r = 0; r < 4; ++r) {
#pragma unroll
      for (int m = 1; m < 16; m <<= 1)
        lsum[rt][r] += __shfl_xor(lsum[rt][r], m, 64);
    }

#pragma unroll
  for (int rt = 0; rt < 2; ++rt) {
#pragma unroll
    for (int nt = 0; nt < 4; ++nt) {
#pragma unroll
      for (int r = 0; r < 4; ++r) {
        int qr = q0 + w * 32 + rt * 16 + qd * 4 + r;
        if (qr < kL) {
          attnout[(size_t)(b * kL + qr) * kC + h * kD + nt * 16 + lr] =
              (f16)(o_acc[rt][nt][r] / lsum[rt][r]);
        }
      }
    }
  }
}

}  // namespace

extern "C" void kernel_launch(void* const* d_in, const int* in_sizes, int n_in,
                              void* d_out, int out_size, void* d_ws,
                              size_t ws_size, hipStream_t stream) {
  const float* x = (const float*)d_in[0];
  const float* pos = (const float*)d_in[1];
  const float* w_qkv = (const float*)d_in[2];
  const float* q_bias = (const float*)d_in[3];
  const float* v_bias = (const float*)d_in[4];
  const float* w_o = (const float*)d_in[5];
  const float* b_o = (const float*)d_in[6];
  float* out = (float*)d_out;

  f16* qkv16 = (f16*)d_ws;                       // kM*kN3
  f16* x16 = qkv16 + (size_t)kM * kN3;           // kM*kC
  f16* wqkv16 = x16 + (size_t)kM * kC;           // kN3*kC
  f16* wo16 = wqkv16 + (size_t)kN3 * kC;         // kC*kC
  f16* ao16 = wo16 + (size_t)kC * kC;            // kM*kC
  float* bias_full = (float*)(ao16 + (size_t)kM * kC);  // kN3 floats

  cvt_f32_f16<<<(kM * kC / 4 + 255) / 256, 256, 0, stream>>>(x, x16, kM * kC);
  cvt_f32_f16<<<(kN3 * kC / 4 + 255) / 256, 256, 0, stream>>>(w_qkv, wqkv16,
                                                              kN3 * kC);
  cvt_f32_f16<<<(kC * kC / 4 + 255) / 256, 256, 0, stream>>>(w_o, wo16,
                                                             kC * kC);
  build_bias_kernel<<<(kN3 + 255) / 256, 256, 0, stream>>>(q_bias, v_bias,
                                                           bias_full);
  gemm256_8ph<f16><<<dim3(kN3 / 256, (kM + 255) / 256), 512, 0, stream>>>(
      x16, wqkv16, bias_full, qkv16, kM, kN3, kC);
  rope_kernel<<<(kM * kH * 32 + 255) / 256, 256, 0, stream>>>(qkv16, pos);
  attn_mfma<<<dim3(kNQT * kH * kB), 256, 0, stream>>>(qkv16, ao16);
  gemm256_8ph<float><<<dim3(kC / 256, (kM + 255) / 256), 512, 0, stream>>>(
      ao16, wo16, b_o, out, kM, kC, kC);
}